// Round 1
// baseline (65.293 us; speedup 1.0000x reference)
//
#include <hip/hip_runtime.h>
#include <hip/hip_bf16.h>

#define BB 16
#define SS 512
#define HH 1024

typedef __attribute__((ext_vector_type(8))) short bhalf8;
typedef __attribute__((ext_vector_type(16))) float f32x16;

static __device__ __forceinline__ unsigned int pack2(float a, float b) {
    __hip_bfloat162 h = __float22bfloat162_rn(make_float2(a, b));
    union { __hip_bfloat162 h; unsigned int u; } cv;
    cv.h = h;
    return cv.u;
}

// One 128x128 output tile per block. A = hidden[b] (S x H, k-contiguous),
// B = W[e] (H x H, d-contiguous). bf16 MFMA 32x32x16, 4 waves, 64x64/wave.
__global__ __launch_bounds__(256, 2)
void moe_gemm_kernel(const float* __restrict__ hid, const float* __restrict__ inp,
                     const int* __restrict__ eidx, const float* __restrict__ W,
                     const float* __restrict__ bias, float* __restrict__ out)
{
    __shared__ unsigned short As[128 * 40];   // [row 0..127][k 0..31], stride 40
    __shared__ unsigned short Ws[128 * 40];   // [d 0..127][k 0..31],  stride 40 (d-major!)

    // XCD-bijective swizzle: 512 blocks, 8 XCDs -> each XCD gets 64 contiguous tiles (2 batches)
    int bx  = blockIdx.x;
    int swz = (bx & 7) * 64 + (bx >> 3);
    int bt   = swz >> 5;       // batch 0..15
    int tile = swz & 31;
    int mt = tile >> 3;        // 0..3   (S tiles)
    int nt = tile & 7;         // 0..7   (H tiles)

    int e = eidx[bt];

    int t    = threadIdx.x;
    int wave = t >> 6;
    int lane = t & 63;
    int l31  = lane & 31;
    int g    = lane >> 5;
    int wm = wave >> 1, wn = wave & 1;

    // ---- A staging: 4 float4/thread, row = f>>3, colgroup = f&7 ----
    const float* aptr[4];
    int a_lds[4];
#pragma unroll
    for (int i = 0; i < 4; ++i) {
        int f = t + i * 256;
        int row = f >> 3, c4 = f & 7;
        aptr[i]  = hid + (size_t)(bt * SS + mt * 128 + row) * HH + c4 * 4;
        a_lds[i] = row * 40 + c4 * 4;
    }
    // ---- W staging: thread owns a 4x4 block; kb = t&7 (k group), db = t>>3 (d group) ----
    int kb = t & 7, db = t >> 3;
    const float* wptr = W + (size_t)e * HH * HH + (size_t)(kb * 4) * HH + nt * 128 + db * 4;

    float4 areg[4];
    float4 wreg[4];

    // prologue loads (k0 = 0)
#pragma unroll
    for (int i = 0; i < 4; ++i)
        areg[i] = *reinterpret_cast<const float4*>(aptr[i]);
#pragma unroll
    for (int r = 0; r < 4; ++r)
        wreg[r] = *reinterpret_cast<const float4*>(wptr + (size_t)r * HH);

    f32x16 acc[4] = {};

    for (int ks = 0; ks < 32; ++ks) {
        __syncthreads();   // previous reads done
        // stage A (bf16)
#pragma unroll
        for (int i = 0; i < 4; ++i) {
            unsigned int u0 = pack2(areg[i].x, areg[i].y);
            unsigned int u1 = pack2(areg[i].z, areg[i].w);
            *reinterpret_cast<uint2*>(&As[a_lds[i]]) = make_uint2(u0, u1);
        }
        // stage W transposed (4x4 register transpose -> d-major LDS)
#pragma unroll
        for (int c = 0; c < 4; ++c) {
            float c0 = (&wreg[0].x)[c];
            float c1 = (&wreg[1].x)[c];
            float c2 = (&wreg[2].x)[c];
            float c3 = (&wreg[3].x)[c];
            unsigned int u0 = pack2(c0, c1);
            unsigned int u1 = pack2(c2, c3);
            *reinterpret_cast<uint2*>(&Ws[(db * 4 + c) * 40 + kb * 4]) = make_uint2(u0, u1);
        }
        __syncthreads();   // tile visible

        // prefetch next tile's globals (hidden under MFMA phase)
        if (ks < 31) {
            int k0 = (ks + 1) * 32;
#pragma unroll
            for (int i = 0; i < 4; ++i)
                areg[i] = *reinterpret_cast<const float4*>(aptr[i] + k0);
#pragma unroll
            for (int r = 0; r < 4; ++r)
                wreg[r] = *reinterpret_cast<const float4*>(wptr + (size_t)(k0 + r) * HH);
        }

        // compute: 2 k-halves x (2m x 2n) MFMAs
#pragma unroll
        for (int kh = 0; kh < 2; ++kh) {
            bhalf8 af[2], bf[2];
#pragma unroll
            for (int mf = 0; mf < 2; ++mf)
                af[mf] = *reinterpret_cast<const bhalf8*>(
                    &As[(wm * 64 + mf * 32 + l31) * 40 + kh * 16 + g * 8]);
#pragma unroll
            for (int nf = 0; nf < 2; ++nf)
                bf[nf] = *reinterpret_cast<const bhalf8*>(
                    &Ws[(wn * 64 + nf * 32 + l31) * 40 + kh * 16 + g * 8]);
#pragma unroll
            for (int mf = 0; mf < 2; ++mf)
#pragma unroll
                for (int nf = 0; nf < 2; ++nf)
                    acc[mf * 2 + nf] = __builtin_amdgcn_mfma_f32_32x32x16_bf16(
                        af[mf], bf[nf], acc[mf * 2 + nf], 0, 0, 0);
        }
    }

    // epilogue: x = acc + bias[e] + input; write f32 to out
    int srow0 = bt * SS + mt * 128 + wm * 64;
    int dcol0 = nt * 128 + wn * 64;
#pragma unroll
    for (int mf = 0; mf < 2; ++mf)
#pragma unroll
        for (int nf = 0; nf < 2; ++nf) {
            f32x16 a = acc[mf * 2 + nf];
            int dcol = dcol0 + nf * 32 + l31;
            float bv = bias[e * HH + dcol];
#pragma unroll
            for (int r = 0; r < 16; ++r) {
                int srow = srow0 + mf * 32 + (r & 3) + 8 * (r >> 2) + 4 * g;
                size_t off = (size_t)srow * HH + dcol;
                out[off] = a[r] + bv + inp[off];
            }
        }
}

// In-place row LayerNorm over H=1024. One block per row, 256 threads, float4/thread.
__global__ __launch_bounds__(256)
void ln_kernel(float* __restrict__ x, const float* __restrict__ gamma,
               const float* __restrict__ beta)
{
    int row = blockIdx.x;
    int t = threadIdx.x;
    size_t base = (size_t)row * HH + t * 4;
    float4 v = *reinterpret_cast<const float4*>(&x[base]);
    float s1 = v.x + v.y + v.z + v.w;
    float s2 = v.x * v.x + v.y * v.y + v.z * v.z + v.w * v.w;
#pragma unroll
    for (int off = 32; off > 0; off >>= 1) {
        s1 += __shfl_xor(s1, off, 64);
        s2 += __shfl_xor(s2, off, 64);
    }
    __shared__ float red[8];
    if ((t & 63) == 0) { red[(t >> 6) * 2] = s1; red[(t >> 6) * 2 + 1] = s2; }
    __syncthreads();
    float S1 = red[0] + red[2] + red[4] + red[6];
    float S2 = red[1] + red[3] + red[5] + red[7];
    float mean = S1 * (1.0f / HH);
    float var  = S2 * (1.0f / HH) - mean * mean;
    float rs = rsqrtf(var + 1e-12f);
    float4 gv = *reinterpret_cast<const float4*>(&gamma[t * 4]);
    float4 bv = *reinterpret_cast<const float4*>(&beta[t * 4]);
    float4 o;
    o.x = (v.x - mean) * rs * gv.x + bv.x;
    o.y = (v.y - mean) * rs * gv.y + bv.y;
    o.z = (v.z - mean) * rs * gv.z + bv.z;
    o.w = (v.w - mean) * rs * gv.w + bv.w;
    *reinterpret_cast<float4*>(&x[base]) = o;
}

extern "C" void kernel_launch(void* const* d_in, const int* in_sizes, int n_in,
                              void* d_out, int out_size, void* d_ws, size_t ws_size,
                              hipStream_t stream) {
    const float* hid   = (const float*)d_in[0];
    const float* inp   = (const float*)d_in[1];
    const int*   eidx  = (const int*)d_in[2];
    const float* W     = (const float*)d_in[3];
    const float* bias  = (const float*)d_in[4];
    const float* gamma = (const float*)d_in[5];
    const float* beta  = (const float*)d_in[6];
    float* out = (float*)d_out;

    moe_gemm_kernel<<<512, 256, 0, stream>>>(hid, inp, eidx, W, bias, out);
    ln_kernel<<<BB * SS, 256, 0, stream>>>(out, gamma, beta);
}